// Round 5
// baseline (4510.342 us; speedup 1.0000x reference)
//
#include <hip/hip_runtime.h>

// ---------------------------------------------------------------------------
// Recurrent ReLU net on MI355X — dataflow version, commit-verified publish.
//   h_{s+1} = relu(h_s @ W^T [+ injection at sensory cols on micro==0])
//   512 sequential steps. 256 persistent WGs (full chip):
//     wg = (col-group cg 0..127) * 2 + (batch-half mh 0..1)
//   Per-wave gating on its 16 K-slab producers replaces the global barrier.
//   Producers READ BACK their own h stores (same-address, same MALL channel,
//   FIFO behind the store) before publishing their flag, closing the
//   flag-beats-data window that broke round 4.
//   W fragments live in VGPRs (hi + 4096*lo fp16 split); LDS = 9 KB scratch.
// ---------------------------------------------------------------------------

#define N_DIM   2048
#define B_DIM   64
#define T_DIM   128
#define NSENS   256
#define NOUT    128
#define NSTEP   512

#define NWG     256
#define THREADS 512
#define SP_S    36            // f16 stride of reduction scratch (2-way banks max)

typedef _Float16 f16x8 __attribute__((ext_vector_type(8)));
typedef _Float16 f16x4 __attribute__((ext_vector_type(4)));
typedef float    f32x4 __attribute__((ext_vector_type(4)));
typedef unsigned long long u64;

// ---------------- setup kernels ----------------

__global__ void k_init(float4* __restrict__ hz, int* __restrict__ inv_sens,
                       int* __restrict__ inv_out, unsigned* __restrict__ flags) {
    int i = blockIdx.x * blockDim.x + threadIdx.x;   // 256*256 threads
    if (i < 32768) hz[i] = make_float4(0.f, 0.f, 0.f, 0.f);   // h0+h1 (512 KB)
    if (i < N_DIM) { inv_sens[i] = -1; inv_out[i] = -1; }
    if (i < NWG) flags[i] = 0u;
}

__global__ void k_inv_scatter(int* inv_sens, int* inv_out,
                              const int* sidx, const int* oidx) {
    int i = threadIdx.x;
    if (i < NSENS) inv_sens[sidx[i]] = i;
    if (i < NOUT)  inv_out[oidx[i]] = i;
}

// inj[t][s][b] = sum_i x[b][t][i]*W_in[s][i] + b_in[s]
__global__ void k_inj(float* __restrict__ inj, const float* __restrict__ inputs,
                      const float* __restrict__ W_in, const float* __restrict__ b_in) {
    int idx = blockIdx.x * blockDim.x + threadIdx.x;   // T*NSENS*B exact
    int b = idx & 63, s = (idx >> 6) & 255, t = idx >> 14;
    float acc = b_in[s];
#pragma unroll
    for (int i2 = 0; i2 < 4; ++i2)
        acc += inputs[(b * T_DIM + t) * 4 + i2] * W_in[s * 4 + i2];
    inj[idx] = acc;
}

// ---------------- device-coherent h access (bypass non-coherent L2s) -------

__device__ __forceinline__ f16x8 load_h8(const _Float16* p) {
    union { u64 u[2]; f16x8 v; } x;
    const u64* q = (const u64*)p;
    x.u[0] = __hip_atomic_load(q,     __ATOMIC_RELAXED, __HIP_MEMORY_SCOPE_AGENT);
    x.u[1] = __hip_atomic_load(q + 1, __ATOMIC_RELAXED, __HIP_MEMORY_SCOPE_AGENT);
    return x.v;
}

// ---------------- main persistent kernel ----------------
// h buffers hold fp16 in MFMA A-fragment order:
//   elem (b, j): f16 offset = ((b>>4)*64 + (j>>5))*512 + (((j>>3)&3)*16 + (b&15))*8 + (j&7)
// so a wave's A-load for (m_tile, k_tile) is one coalesced 1 KB read at
// hbuf[(m_tile*64+kt)*512 + lane*8].

__global__ __launch_bounds__(THREADS, 2)
void rnn_main(const float* __restrict__ W_rec, const float* __restrict__ inj,
              const int* __restrict__ inv_sens, const int* __restrict__ inv_out,
              _Float16* __restrict__ h0, _Float16* __restrict__ h1,
              _Float16* __restrict__ hc /* [T][NOUT][B] */,
              unsigned* __restrict__ flags /* [2 planes][128 cg], 4-B packed */)
{
    __shared__ _Float16 sp[128 * SP_S];               // 9216 B

    const int tid   = threadIdx.x;
    const int wg    = blockIdx.x;
    const int mh    = wg & 1;        // batch-half plane (rows mh*32..+31)
    const int cg    = wg >> 1;       // col-group (16 cols)
    const int jbase = cg * 16;

    const int lane = tid & 63;
    const int wv   = tid >> 6;       // wave id = K-slab (k-tiles wv*8..wv*8+7)
    const int lrow = lane & 15;
    const int quad = lane >> 4;

    // ---- W fragments in registers: hi + 4096*lo fp16 split, loaded once ----
    f16x8 bh[8], bl[8];
    {
        const float* wr = W_rec + (size_t)(jbase + lrow) * N_DIM + wv * 256 + quad * 8;
#pragma unroll
        for (int ks = 0; ks < 8; ++ks) {
            const float4 wa = ((const float4*)(wr + ks * 32))[0];
            const float4 wb = ((const float4*)(wr + ks * 32))[1];
            const float w8[8] = {wa.x, wa.y, wa.z, wa.w, wb.x, wb.y, wb.z, wb.w};
#pragma unroll
            for (int e = 0; e < 8; ++e) {
                const _Float16 hi = (_Float16)w8[e];
                bh[ks][e] = hi;
                bl[ks][e] = (_Float16)((w8[e] - (float)hi) * 4096.0f);
            }
        }
    }

    // ---- epilogue constants (threads 0..255 active): one (b, j-pair) each ----
    const int ep_bl = tid >> 3;            // local batch row 0..31
    const int ep_b  = mh * 32 + ep_bl;     // global batch row
    const int ep_j0 = (tid & 7) * 2;       // local col pair (even)
    const int ej    = jbase + ep_j0;
    int ep_sA = -1, ep_sB = -1, ep_uA = -1, ep_uB = -1, ep_off = 0;
    if (tid < 256) {
        ep_sA = inv_sens[ej];  ep_sB = inv_sens[ej + 1];
        ep_uA = inv_out[ej];   ep_uB = inv_out[ej + 1];
        ep_off = (((ep_b >> 4) * 64 + (ej >> 5)) << 9)
               + ((((ej >> 3) & 3) * 16 + (ep_b & 15)) << 3) + (ej & 7);
    }

    const unsigned* gate   = flags + mh * 128 + wv * 16 + lrow;  // lanes 0..15 poll
    unsigned*       myflag = flags + mh * 128 + cg;

    for (int step = 0; step < NSTEP; ++step) {
        const int t = step >> 2, micro = step & 3;
        const _Float16* __restrict__ hcur  = (step & 1) ? h1 : h0;
        _Float16* __restrict__       hnext = (step & 1) ? h0 : h1;

        // ---- per-wave gate: our 16 K-slab producers finished step-1 ----
        if (lane < 16) {
            while (__hip_atomic_load(gate, __ATOMIC_RELAXED,
                                     __HIP_MEMORY_SCOPE_AGENT) < (unsigned)step) {
                __builtin_amdgcn_s_sleep(1);
            }
        }
        __asm__ volatile("" ::: "memory");   // keep A-loads after the gate

        // ---- all 16 A-fragment loads in flight ----
        f16x8 A[8][2];
#pragma unroll
        for (int ks = 0; ks < 8; ++ks) {
            const int kt = wv * 8 + ks;
#pragma unroll
            for (int mt = 0; mt < 2; ++mt)
                A[ks][mt] = load_h8(hcur + (((mh * 2 + mt) * 64 + kt) << 9) + lane * 8);
        }

        f32x4 acch[2], accl[2];
#pragma unroll
        for (int mt = 0; mt < 2; ++mt) {
            acch[mt] = (f32x4){0.f, 0.f, 0.f, 0.f};
            accl[mt] = (f32x4){0.f, 0.f, 0.f, 0.f};
        }

#pragma unroll
        for (int ks = 0; ks < 8; ++ks)
#pragma unroll
            for (int mt = 0; mt < 2; ++mt) {
                acch[mt] = __builtin_amdgcn_mfma_f32_16x16x32_f16(A[ks][mt], bh[ks], acch[mt], 0, 0, 0);
                accl[mt] = __builtin_amdgcn_mfma_f32_16x16x32_f16(A[ks][mt], bl[ks], accl[mt], 0, 0, 0);
            }

        // ---- K-slab partial (hi + lo/4096) to LDS scratch ----
#pragma unroll
        for (int mt = 0; mt < 2; ++mt) {
            f16x4 pv;
#pragma unroll
            for (int r = 0; r < 4; ++r)
                pv[r] = (_Float16)(acch[mt][r] + accl[mt][r] * 2.44140625e-4f);
            *(f16x4*)(sp + (wv * 16 + lrow) * SP_S + mt * 16 + quad * 4) = pv;
        }
        __syncthreads();   // all 8 gates passed => plane flags >= step
                           // => all readers of hnext (step-1) are done => WAR safe

        // ---- epilogue: 256 threads, one (b, j-pair) each ----
        if (tid < 256) {
            float vA = 0.f, vB = 0.f;
#pragma unroll
            for (int s8 = 0; s8 < 8; ++s8) {
                vA += (float)sp[(s8 * 16 + ep_j0    ) * SP_S + ep_bl];
                vB += (float)sp[(s8 * 16 + ep_j0 + 1) * SP_S + ep_bl];
            }
            if (micro == 0) {
                if (ep_sA >= 0) vA += inj[(t * NSENS + ep_sA) * B_DIM + ep_b];
                if (ep_sB >= 0) vB += inj[(t * NSENS + ep_sB) * B_DIM + ep_b];
            }
            union { _Float16 h[2]; unsigned u; } pk;
            pk.h[0] = (_Float16)fmaxf(vA, 0.0f);
            pk.h[1] = (_Float16)fmaxf(vB, 0.0f);
            __hip_atomic_store((unsigned*)(hnext + ep_off), pk.u,
                               __ATOMIC_RELAXED, __HIP_MEMORY_SCOPE_AGENT);
            // ---- commit verification: re-load own word through the same MALL
            // channel (FIFO behind the store). Address & result laundered so
            // the compiler can neither forward the store value nor drop the load.
            unsigned* rb_addr = (unsigned*)(hnext + ep_off);
            __asm__ volatile("" : "+v"(rb_addr));
            unsigned rb = __hip_atomic_load(rb_addr, __ATOMIC_RELAXED,
                                            __HIP_MEMORY_SCOPE_AGENT);
            __asm__ volatile("" :: "v"(rb));
            if (micro == 3) {
                if (ep_uA >= 0) hc[(t * NOUT + ep_uA) * B_DIM + ep_b] = pk.h[0];
                if (ep_uB >= 0) hc[(t * NOUT + ep_uB) * B_DIM + ep_b] = pk.h[1];
            }
        }
        __syncthreads();   // drains readback loads too: h committed at MALL
        if (tid == 0)
            __hip_atomic_store(myflag, (unsigned)(step + 1),
                               __ATOMIC_RELAXED, __HIP_MEMORY_SCOPE_AGENT);
    }
}

// ---------------- final readout: out[b][t][o] = hc[t][:][b] . W_out[o][:] + b_out ----

__global__ __launch_bounds__(128)
void k_readout(float* __restrict__ out, const _Float16* __restrict__ hc,
               const float* __restrict__ W_out, const float* __restrict__ b_out) {
    __shared__ _Float16 sh[NOUT * B_DIM];
    const int t = blockIdx.x, tid = threadIdx.x;
    const unsigned int* src = (const unsigned int*)(hc + (size_t)t * NOUT * B_DIM);
    for (int i = tid; i < NOUT * B_DIM / 2; i += 128)
        ((unsigned int*)sh)[i] = src[i];
    __syncthreads();
    const int o = tid >> 6, b = tid & 63;
    float acc = b_out[o];
#pragma unroll 8
    for (int u = 0; u < NOUT; ++u)
        acc += (float)sh[u * B_DIM + b] * W_out[o * NOUT + u];
    out[(b * T_DIM + t) * 2 + o] = acc;
}

// ---------------- host launch ----------------

extern "C" void kernel_launch(void* const* d_in, const int* in_sizes, int n_in,
                              void* d_out, int out_size, void* d_ws, size_t ws_size,
                              hipStream_t stream) {
    const float* inputs = (const float*)d_in[0];
    const float* W_rec  = (const float*)d_in[1];
    const float* W_in   = (const float*)d_in[2];
    const float* b_in   = (const float*)d_in[3];
    const float* W_out  = (const float*)d_in[4];
    const float* b_out  = (const float*)d_in[5];
    const int*   sidx   = (const int*)d_in[6];
    const int*   oidx   = (const int*)d_in[7];

    char* ws = (char*)d_ws;
    float*    inj      = (float*)ws;                               // 8,388,608 B
    _Float16* h0       = (_Float16*)(ws + 8388608);                //   262,144 B
    _Float16* h1       = (_Float16*)(ws + 8388608 + 262144);       //   262,144 B
    _Float16* hc       = (_Float16*)(ws + 8388608 + 2 * 262144);   // 2,097,152 B
    int*      inv_sens = (int*)(ws + 8388608 + 2 * 262144 + 2097152);
    int*      inv_out  = inv_sens + N_DIM;
    unsigned* flags    = (unsigned*)(inv_out + N_DIM);             // 1,024 B

    k_init<<<256, 256, 0, stream>>>((float4*)h0, inv_sens, inv_out, flags);
    k_inv_scatter<<<1, 256, 0, stream>>>(inv_sens, inv_out, sidx, oidx);
    k_inj<<<(T_DIM * NSENS * B_DIM) / 256, 256, 0, stream>>>(inj, inputs, W_in, b_in);

    rnn_main<<<NWG, THREADS, 0, stream>>>(
        W_rec, inj, inv_sens, inv_out, h0, h1, hc, flags);

    k_readout<<<T_DIM, 128, 0, stream>>>((float*)d_out, hc, W_out, b_out);
}

// Round 6
// 3097.371 us; speedup vs baseline: 1.4562x; 1.4562x over previous
//
#include <hip/hip_runtime.h>

// ---------------------------------------------------------------------------
// Recurrent ReLU net on MI355X — sign-validated dataflow, CW=32.
//   h_{s+1} = relu(h_s @ W^T [+ injection at sensory cols on micro==0])
//   256 persistent WGs: wg -> plane = wg&3 (16 batch rows), cg = wg>>2 (32 cols).
//   h exchange: fp16 in MFMA A-fragment order via sc1 (MALL-coherent) ops.
//   Validity protocol: h >= 0 (ReLU); even buffer stores sign-bit SET (-h/-0),
//   odd buffer sign-bit CLEAR. Consumers verify every 4-B word by sign bit and
//   retry stale fragments -> no readback, flags only advisory (cheap pre-gate).
//   WAR (2 buffers): a WG writes h_{s+2} only after validating ALL h_{s+1},
//   which requires every producer (incl. any slow reader of h_s) to have
//   finished its step-s reads (intra-WG sync before epilogue). Same as r4/r5.
//   W: hi + 4096*lo fp16 split resident in VGPRs (128/lane).
// ---------------------------------------------------------------------------

#define N_DIM   2048
#define B_DIM   64
#define T_DIM   128
#define NSENS   256
#define NOUT    128
#define NSTEP   512

#define NWG     256
#define THREADS 512
#define CW      32
#define SP_S    20            // f16 stride: 40 B rows -> 8B-aligned f16x4, ~2-way banks

typedef _Float16 f16x8 __attribute__((ext_vector_type(8)));
typedef _Float16 f16x4 __attribute__((ext_vector_type(4)));
typedef float    f32x4 __attribute__((ext_vector_type(4)));
typedef unsigned long long u64;

#define SIGN_M32 0x80008000u
#define SIGN_M64 0x8000800080008000ULL

// ---------------- setup kernels ----------------

__global__ void k_init(uint4* __restrict__ hz, int* __restrict__ inv_sens,
                       int* __restrict__ inv_out, unsigned* __restrict__ flags) {
    int i = blockIdx.x * blockDim.x + threadIdx.x;   // 32768 threads
    // h0+h1 = 512 KB: fill with 0x8000 pattern.
    //   h0 (even buffer): sign SET = VALID for step 0, value -0 -> 0.  OK
    //   h1 (odd buffer):  sign SET = INVALID for step-1 consumers.    OK
    if (i < 32768) hz[i] = make_uint4(SIGN_M32, SIGN_M32, SIGN_M32, SIGN_M32);
    if (i < N_DIM) { inv_sens[i] = -1; inv_out[i] = -1; }
    if (i < NWG) flags[i] = 0u;
}

__global__ void k_inv_scatter(int* inv_sens, int* inv_out,
                              const int* sidx, const int* oidx) {
    int i = threadIdx.x;
    if (i < NSENS) inv_sens[sidx[i]] = i;
    if (i < NOUT)  inv_out[oidx[i]] = i;
}

// inj[t][s][b] = sum_i x[b][t][i]*W_in[s][i] + b_in[s]
__global__ void k_inj(float* __restrict__ inj, const float* __restrict__ inputs,
                      const float* __restrict__ W_in, const float* __restrict__ b_in) {
    int idx = blockIdx.x * blockDim.x + threadIdx.x;   // T*NSENS*B exact
    int b = idx & 63, s = (idx >> 6) & 255, t = idx >> 14;
    float acc = b_in[s];
#pragma unroll
    for (int i2 = 0; i2 < 4; ++i2)
        acc += inputs[(b * T_DIM + t) * 4 + i2] * W_in[s * 4 + i2];
    inj[idx] = acc;
}

// ---------------- coherent (MALL) access helpers ----------------

__device__ __forceinline__ u64 ld_u64(const u64* q) {
    return __hip_atomic_load(q, __ATOMIC_RELAXED, __HIP_MEMORY_SCOPE_AGENT);
}

// ---------------- main persistent kernel ----------------
// h buffers: fp16 in MFMA A-fragment order.
//   elem (b, j): f16 offset = ((b>>4)*64 + (j>>5))*512 + (((j>>3)&3)*16 + (b&15))*8 + (j&7)
// wave A-load for (plane, kt) = one coalesced 1 KB read at [(plane*64+kt)*512 + lane*8].

__global__ __launch_bounds__(THREADS, 2)
void rnn_main(const float* __restrict__ W_rec, const float* __restrict__ inj,
              const int* __restrict__ inv_sens, const int* __restrict__ inv_out,
              _Float16* __restrict__ h0, _Float16* __restrict__ h1,
              _Float16* __restrict__ hc /* [T][NOUT][B] */,
              unsigned* __restrict__ flags /* [4 planes][64 cg] */)
{
    __shared__ _Float16 sp[256 * SP_S];               // 10240 B

    const int tid   = threadIdx.x;
    const int wg    = blockIdx.x;
    const int pl    = wg & 3;        // plane: batch rows pl*16..+15
    const int cg    = wg >> 2;       // col group: cols cg*32..+31
    const int jbase = cg * CW;

    const int lane = tid & 63;
    const int wv   = tid >> 6;       // wave = K-slab (k-tiles wv*8..wv*8+7)
    const int lrow = lane & 15;
    const int quad = lane >> 4;

    // ---- W fragments in VGPRs: hi + 4096*lo fp16 split (128 regs/lane) ----
    f16x8 bh[8][2], bl[8][2];
#pragma unroll
    for (int nt = 0; nt < 2; ++nt) {
        const float* wr = W_rec + (size_t)(jbase + nt * 16 + lrow) * N_DIM
                        + wv * 256 + quad * 8;
#pragma unroll
        for (int ks = 0; ks < 8; ++ks) {
            const float4 wa = ((const float4*)(wr + ks * 32))[0];
            const float4 wb = ((const float4*)(wr + ks * 32))[1];
            const float w8[8] = {wa.x, wa.y, wa.z, wa.w, wb.x, wb.y, wb.z, wb.w};
#pragma unroll
            for (int e = 0; e < 8; ++e) {
                const _Float16 hi = (_Float16)w8[e];
                bh[ks][nt][e] = hi;
                bl[ks][nt][e] = (_Float16)((w8[e] - (float)hi) * 4096.0f);
            }
        }
    }

    // ---- epilogue constants (threads 0..255): one (b, col-pair) each ----
    const int ep_bl = tid >> 4;            // local batch row 0..15
    const int ep_b  = pl * 16 + ep_bl;     // global batch row
    const int ep_jp = tid & 15;            // col pair index
    const int ej    = jbase + ep_jp * 2;   // global col, even
    int ep_sA = -1, ep_sB = -1, ep_uA = -1, ep_uB = -1, ep_off = 0;
    if (tid < 256) {
        ep_sA = inv_sens[ej];  ep_sB = inv_sens[ej + 1];
        ep_uA = inv_out[ej];   ep_uB = inv_out[ej + 1];
        ep_off = ((pl * 64 + (ej >> 5)) << 9)
               + ((((ej >> 3) & 3) * 16 + ep_bl) << 3) + (ej & 7);
    }

    // advisory pre-gate: lanes 0..7 each poll one producer cg's flag (coalesced 32B)
    const unsigned* gate = flags + pl * 64 + wv * 8 + (lane & 7);

    for (int step = 0; step < NSTEP; ++step) {
        const int t = step >> 2, micro = step & 3;
        const bool evenbuf = (step & 1) == 0;                 // reading h0?
        const _Float16* __restrict__ hcur  = evenbuf ? h0 : h1;
        _Float16* __restrict__       hnext = evenbuf ? h1 : h0;

        // ---- advisory gate (correctness does not depend on it) ----
        if (lane < 8) {
            while (__hip_atomic_load(gate, __ATOMIC_RELAXED,
                                     __HIP_MEMORY_SCOPE_AGENT) < (unsigned)step) {
                __builtin_amdgcn_s_sleep(1);
            }
        }
        __asm__ volatile("" ::: "memory");

        // ---- payload: 8 fragments, sign-validated with per-fragment retry ----
        const u64* hb = (const u64*)(hcur + ((pl * 64 + wv * 8) << 9) + lane * 8);
        u64 a0[8], a1[8];
#pragma unroll
        for (int f = 0; f < 8; ++f) {
            a0[f] = ld_u64(hb + f * 128);       // frag f at +f*512 f16 = +f*128 u64
            a1[f] = ld_u64(hb + f * 128 + 1);
        }
        unsigned live = 0xFFu;
        while (true) {
#pragma unroll
            for (int f = 0; f < 8; ++f) if (live & (1u << f)) {
                const u64 x_and = a0[f] & a1[f], x_or = a0[f] | a1[f];
                const bool ok = evenbuf ? ((x_and & SIGN_M64) == SIGN_M64)
                                        : ((x_or  & SIGN_M64) == 0);
                if (ok) live &= ~(1u << f);
            }
            if (!__any((int)live)) break;
            __builtin_amdgcn_s_sleep(1);
#pragma unroll
            for (int f = 0; f < 8; ++f) if (live & (1u << f)) {
                a0[f] = ld_u64(hb + f * 128);
                a1[f] = ld_u64(hb + f * 128 + 1);
            }
        }
        // restore sign (even buffer holds -h) and reinterpret as f16x8
        f16x8 A[8];
#pragma unroll
        for (int f = 0; f < 8; ++f) {
            union { u64 u[2]; f16x8 v; } c;
            c.u[0] = evenbuf ? (a0[f] ^ SIGN_M64) : a0[f];
            c.u[1] = evenbuf ? (a1[f] ^ SIGN_M64) : a1[f];
            A[f] = c.v;
        }

        f32x4 acch[2], accl[2];
#pragma unroll
        for (int nt = 0; nt < 2; ++nt) {
            acch[nt] = (f32x4){0.f, 0.f, 0.f, 0.f};
            accl[nt] = (f32x4){0.f, 0.f, 0.f, 0.f};
        }
#pragma unroll
        for (int ks = 0; ks < 8; ++ks)
#pragma unroll
            for (int nt = 0; nt < 2; ++nt) {
                acch[nt] = __builtin_amdgcn_mfma_f32_16x16x32_f16(A[ks], bh[ks][nt], acch[nt], 0, 0, 0);
                accl[nt] = __builtin_amdgcn_mfma_f32_16x16x32_f16(A[ks], bl[ks][nt], accl[nt], 0, 0, 0);
            }

        // ---- K-slab partial (hi + lo/4096) to LDS scratch ----
        // C/D: n = lrow (within nt), m(b_local) = quad*4 + r
#pragma unroll
        for (int nt = 0; nt < 2; ++nt) {
            f16x4 pv;
#pragma unroll
            for (int r = 0; r < 4; ++r)
                pv[r] = (_Float16)(acch[nt][r] + accl[nt][r] * 2.44140625e-4f);
            *(f16x4*)(sp + (wv * 32 + nt * 16 + lrow) * SP_S + quad * 4) = pv;
        }
        __syncthreads();   // all waves consumed h_step  (WAR anchor)

        // ---- epilogue: 256 threads, one (b, col-pair) each ----
        if (tid < 256) {
            float vA = 0.f, vB = 0.f;
#pragma unroll
            for (int s8 = 0; s8 < 8; ++s8) {
                vA += (float)sp[(s8 * 32 + ep_jp * 2    ) * SP_S + ep_bl];
                vB += (float)sp[(s8 * 32 + ep_jp * 2 + 1) * SP_S + ep_bl];
            }
            if (micro == 0) {
                if (ep_sA >= 0) vA += inj[(t * NSENS + ep_sA) * B_DIM + ep_b];
                if (ep_sB >= 0) vB += inj[(t * NSENS + ep_sB) * B_DIM + ep_b];
            }
            union { _Float16 h[2]; unsigned u; } pk;
            pk.h[0] = (_Float16)fmaxf(vA, 0.0f);
            pk.h[1] = (_Float16)fmaxf(vB, 0.0f);
            if (micro == 3) {
                if (ep_uA >= 0) hc[(t * NOUT + ep_uA) * B_DIM + ep_b] = pk.h[0];
                if (ep_uB >= 0) hc[(t * NOUT + ep_uB) * B_DIM + ep_b] = pk.h[1];
            }
            // hnext==h0 (even buffer) <=> step odd: set sign bits (h>=0, so OR)
            pk.u |= evenbuf ? 0u : SIGN_M32;
            __hip_atomic_store((unsigned*)(hnext + ep_off), pk.u,
                               __ATOMIC_RELAXED, __HIP_MEMORY_SCOPE_AGENT);
        }
        __syncthreads();   // drain all waves' stores (makes advisory flag reliable)
        if (tid == 0)
            __hip_atomic_store(flags + pl * 64 + cg, (unsigned)(step + 1),
                               __ATOMIC_RELAXED, __HIP_MEMORY_SCOPE_AGENT);
    }
}

// ---------------- final readout: out[b][t][o] = hc[t][:][b] . W_out[o][:] + b_out ----

__global__ __launch_bounds__(128)
void k_readout(float* __restrict__ out, const _Float16* __restrict__ hc,
               const float* __restrict__ W_out, const float* __restrict__ b_out) {
    __shared__ _Float16 sh[NOUT * B_DIM];
    const int t = blockIdx.x, tid = threadIdx.x;
    const unsigned int* src = (const unsigned int*)(hc + (size_t)t * NOUT * B_DIM);
    for (int i = tid; i < NOUT * B_DIM / 2; i += 128)
        ((unsigned int*)sh)[i] = src[i];
    __syncthreads();
    const int o = tid >> 6, b = tid & 63;
    float acc = b_out[o];
#pragma unroll 8
    for (int u = 0; u < NOUT; ++u)
        acc += (float)sh[u * B_DIM + b] * W_out[o * NOUT + u];
    out[(b * T_DIM + t) * 2 + o] = acc;
}

// ---------------- host launch ----------------

extern "C" void kernel_launch(void* const* d_in, const int* in_sizes, int n_in,
                              void* d_out, int out_size, void* d_ws, size_t ws_size,
                              hipStream_t stream) {
    const float* inputs = (const float*)d_in[0];
    const float* W_rec  = (const float*)d_in[1];
    const float* W_in   = (const float*)d_in[2];
    const float* b_in   = (const float*)d_in[3];
    const float* W_out  = (const float*)d_in[4];
    const float* b_out  = (const float*)d_in[5];
    const int*   sidx   = (const int*)d_in[6];
    const int*   oidx   = (const int*)d_in[7];

    char* ws = (char*)d_ws;
    float*    inj      = (float*)ws;                               // 8,388,608 B
    _Float16* h0       = (_Float16*)(ws + 8388608);                //   262,144 B
    _Float16* h1       = (_Float16*)(ws + 8388608 + 262144);       //   262,144 B
    _Float16* hc       = (_Float16*)(ws + 8388608 + 2 * 262144);   // 2,097,152 B
    int*      inv_sens = (int*)(ws + 8388608 + 2 * 262144 + 2097152);
    int*      inv_out  = inv_sens + N_DIM;
    unsigned* flags    = (unsigned*)(inv_out + N_DIM);             // 1,024 B

    k_init<<<128, 256, 0, stream>>>((uint4*)h0, inv_sens, inv_out, flags);
    k_inv_scatter<<<1, 256, 0, stream>>>(inv_sens, inv_out, sidx, oidx);
    k_inj<<<(T_DIM * NSENS * B_DIM) / 256, 256, 0, stream>>>(inj, inputs, W_in, b_in);

    rnn_main<<<NWG, THREADS, 0, stream>>>(
        W_rec, inj, inv_sens, inv_out, h0, h1, hc, flags);

    k_readout<<<T_DIM, 128, 0, stream>>>((float*)d_out, hc, W_out, b_out);
}

// Round 7
// 2870.898 us; speedup vs baseline: 1.5711x; 1.0789x over previous
//
#include <hip/hip_runtime.h>

// ---------------------------------------------------------------------------
// Recurrent ReLU net on MI355X — flagless sign-parity dataflow, CW=32.
//   h_{s+1} = relu(h_s @ W^T [+ injection at sensory cols on micro==0])
//   256 persistent WGs: plane = wg&3 (16 batch rows), cg = wg>>2 (32 cols).
//   h exchange: fp16 MFMA-A-fragment layout via agent-scope (MALL) ops.
//   Sync protocol (NO flags, NO readback):
//     parity(step) = step&1: even steps store -h (sign SET), odd store +h.
//     3 h buffers, buffer = step%3. Buffer cycle (3) is coprime with parity
//     cycle (2), so any overwrite flips the expected sign -> staleness is
//     always detectable per 4-B word; consumers retry invalid fragments and
//     MFMA each fragment as soon as all 64 lanes see it valid.
//     WAR: WG writes step s+3 only after validating s+2, which transitively
//     requires every WG of the plane to have stored s+1, i.e. finished
//     reading s (intra-WG __syncthreads before epilogue). Proven safe.
//   W: hi fp16 in LDS (128 KB, per-wave fragment blocks), lo fp16 in VGPRs.
// ---------------------------------------------------------------------------

#define N_DIM   2048
#define B_DIM   64
#define T_DIM   128
#define NSENS   256
#define NOUT    128
#define NSTEP   512

#define NWG     256
#define THREADS 512
#define CW      32
#define SP_S    20                     // f16 stride of reduction scratch rows
#define SP_HALF (256 * SP_S)           // f16 per scratch half (double-buffered)
#define LDS_W_F16 (CW * N_DIM)         // 65536 f16 = 128 KB hi
#define SMEM_MAIN (LDS_W_F16 * 2 + 2 * SP_HALF * 2)   // 131072 + 20480 = 151552

typedef _Float16 f16x8 __attribute__((ext_vector_type(8)));
typedef _Float16 f16x4 __attribute__((ext_vector_type(4)));
typedef float    f32x4 __attribute__((ext_vector_type(4)));
typedef unsigned long long u64;

#define SIGN_M32 0x80008000u
#define SIGN_M64 0x8000800080008000ULL

// ---------------- setup kernels ----------------

__global__ void k_init(uint4* __restrict__ hz, int* __restrict__ inv_sens,
                       int* __restrict__ inv_out) {
    int i = blockIdx.x * blockDim.x + threadIdx.x;   // 49152 threads
    // h0,h1 = 0x8000 pattern (h0: valid-even zeros (-0); h1: invalid-for-odd)
    // h2 = 0x0000 (invalid-for-even)
    hz[i] = (i < 32768) ? make_uint4(SIGN_M32, SIGN_M32, SIGN_M32, SIGN_M32)
                        : make_uint4(0u, 0u, 0u, 0u);
    if (i < N_DIM) { inv_sens[i] = -1; inv_out[i] = -1; }
}

__global__ void k_inv_scatter(int* inv_sens, int* inv_out,
                              const int* sidx, const int* oidx) {
    int i = threadIdx.x;
    if (i < NSENS) inv_sens[sidx[i]] = i;
    if (i < NOUT)  inv_out[oidx[i]] = i;
}

// inj[t][s][b] = sum_i x[b][t][i]*W_in[s][i] + b_in[s]
__global__ void k_inj(float* __restrict__ inj, const float* __restrict__ inputs,
                      const float* __restrict__ W_in, const float* __restrict__ b_in) {
    int idx = blockIdx.x * blockDim.x + threadIdx.x;   // T*NSENS*B exact
    int b = idx & 63, s = (idx >> 6) & 255, t = idx >> 14;
    float acc = b_in[s];
#pragma unroll
    for (int i2 = 0; i2 < 4; ++i2)
        acc += inputs[(b * T_DIM + t) * 4 + i2] * W_in[s * 4 + i2];
    inj[idx] = acc;
}

// ---------------- coherent (MALL) access helper ----------------

__device__ __forceinline__ u64 ld_u64(const u64* q) {
    return __hip_atomic_load(q, __ATOMIC_RELAXED, __HIP_MEMORY_SCOPE_AGENT);
}

// ---------------- main persistent kernel ----------------
// h buffers: fp16 in MFMA A-fragment order.
//   elem (b, j): f16 offset = ((b>>4)*64 + (j>>5))*512 + (((j>>3)&3)*16 + (b&15))*8 + (j&7)
// Fragment (pl, kt) is 1 KB, produced entirely by WG (pl, cg=kt).
// Wave A-load: one coalesced 1 KB read at [(pl*64+kt)*512 + lane*8].

__global__ __launch_bounds__(THREADS, 2)
void rnn_main(const float* __restrict__ W_rec, const float* __restrict__ inj,
              const int* __restrict__ inv_sens, const int* __restrict__ inv_out,
              _Float16* __restrict__ h0, _Float16* __restrict__ h1,
              _Float16* __restrict__ h2, _Float16* __restrict__ hc /* [T][NOUT][B] */)
{
    extern __shared__ _Float16 smem[];
    _Float16* w_hi = smem;                  // [128 blocks][512]  (kt*2+nt major)
    _Float16* sp   = smem + LDS_W_F16;      // [2][256][SP_S]

    const int tid   = threadIdx.x;
    const int wg    = blockIdx.x;
    const int pl    = wg & 3;        // plane: batch rows pl*16..+15
    const int cg    = wg >> 2;       // col group: cols cg*32..+31
    const int jbase = cg * CW;

    const int lane = tid & 63;
    const int wv   = tid >> 6;       // wave = K-slab (k-tiles wv*8..wv*8+7)
    const int lrow = lane & 15;
    const int quad = lane >> 4;

    // ---- stage W: hi -> LDS (each wave writes only its own blocks),
    //               lo (x4096 residual) -> VGPRs (64 regs) ----
    f16x8 blo[8][2];
#pragma unroll
    for (int nt = 0; nt < 2; ++nt) {
        const float* wr = W_rec + (size_t)(jbase + nt * 16 + lrow) * N_DIM
                        + wv * 256 + quad * 8;
#pragma unroll
        for (int ks = 0; ks < 8; ++ks) {
            const float4 wa = ((const float4*)(wr + ks * 32))[0];
            const float4 wb = ((const float4*)(wr + ks * 32))[1];
            const float w8[8] = {wa.x, wa.y, wa.z, wa.w, wb.x, wb.y, wb.z, wb.w};
            f16x8 hi8;
#pragma unroll
            for (int e = 0; e < 8; ++e) {
                const _Float16 hi = (_Float16)w8[e];
                hi8[e] = hi;
                blo[ks][nt][e] = (_Float16)((w8[e] - (float)hi) * 4096.0f);
            }
            *(f16x8*)(w_hi + ((((wv * 8 + ks) * 2 + nt)) << 9) + lane * 8) = hi8;
        }
    }

    // ---- epilogue constants (threads 0..255): one (b, col-pair) each ----
    const int ep_bl = tid >> 4;            // local batch row 0..15
    const int ep_b  = pl * 16 + ep_bl;     // global batch row
    const int ep_jp = tid & 15;            // col pair index
    const int ej    = jbase + ep_jp * 2;   // global col, even
    int ep_sA = -1, ep_sB = -1, ep_uA = -1, ep_uB = -1, ep_off = 0;
    if (tid < 256) {
        ep_sA = inv_sens[ej];  ep_sB = inv_sens[ej + 1];
        ep_uA = inv_out[ej];   ep_uB = inv_out[ej + 1];
        ep_off = ((pl * 64 + cg) << 9)
               + ((((ej >> 3) & 3) * 16 + ep_bl) << 3) + (ej & 7);
    }
    __syncthreads();

    _Float16* bA = h0;   // current (read)
    _Float16* bB = h1;   // next (write)
    _Float16* bC = h2;

    for (int step = 0; step < NSTEP; ++step) {
        const int t = step >> 2, micro = step & 3;
        const bool expSet = (step & 1) == 0;     // parity of data being read

        // ---- hi fragments from LDS (always valid) ----
        f16x8 bh[8][2];
#pragma unroll
        for (int ks = 0; ks < 8; ++ks)
#pragma unroll
            for (int nt = 0; nt < 2; ++nt)
                bh[ks][nt] = *(const f16x8*)(w_hi + (((wv * 8 + ks) * 2 + nt) << 9) + lane * 8);

        // ---- speculative payload loads ----
        const u64* hb = (const u64*)(bA + ((pl * 64 + wv * 8) << 9) + lane * 8);
        u64 a0[8], a1[8];
#pragma unroll
        for (int f = 0; f < 8; ++f) {
            a0[f] = ld_u64(hb + f * 128);
            a1[f] = ld_u64(hb + f * 128 + 1);
        }

        f32x4 acch[2], accl[2];
#pragma unroll
        for (int nt = 0; nt < 2; ++nt) {
            acch[nt] = (f32x4){0.f, 0.f, 0.f, 0.f};
            accl[nt] = (f32x4){0.f, 0.f, 0.f, 0.f};
        }

        // ---- validate + consume: MFMA each fragment once all lanes see it ----
        unsigned live = 0xFFu;
        while (live) {
#pragma unroll
            for (int f = 0; f < 8; ++f) if (live & (1u << f)) {
                const u64 band = a0[f] & a1[f];
                const u64 bor  = a0[f] | a1[f];
                const bool ok = expSet ? ((band & SIGN_M64) == SIGN_M64)
                                       : ((bor  & SIGN_M64) == 0);
                if (__all((int)ok)) {
                    union { u64 u[2]; f16x8 v; } c;
                    c.u[0] = expSet ? (a0[f] ^ SIGN_M64) : a0[f];
                    c.u[1] = expSet ? (a1[f] ^ SIGN_M64) : a1[f];
                    const f16x8 Af = c.v;
                    acch[0] = __builtin_amdgcn_mfma_f32_16x16x32_f16(Af, bh[f][0], acch[0], 0, 0, 0);
                    accl[0] = __builtin_amdgcn_mfma_f32_16x16x32_f16(Af, blo[f][0], accl[0], 0, 0, 0);
                    acch[1] = __builtin_amdgcn_mfma_f32_16x16x32_f16(Af, bh[f][1], acch[1], 0, 0, 0);
                    accl[1] = __builtin_amdgcn_mfma_f32_16x16x32_f16(Af, blo[f][1], accl[1], 0, 0, 0);
                    live &= ~(1u << f);
                }
            }
            if (live) {
                __builtin_amdgcn_s_sleep(1);
#pragma unroll
                for (int f = 0; f < 8; ++f) if (live & (1u << f)) {
                    a0[f] = ld_u64(hb + f * 128);
                    a1[f] = ld_u64(hb + f * 128 + 1);
                }
            }
        }

        // ---- K-slab partial (hi + lo/4096) to LDS scratch (step-parity half) ----
        _Float16* sph = sp + (step & 1) * SP_HALF;
#pragma unroll
        for (int nt = 0; nt < 2; ++nt) {
            f16x4 pv;
#pragma unroll
            for (int r = 0; r < 4; ++r)
                pv[r] = (_Float16)(acch[nt][r] + accl[nt][r] * 2.44140625e-4f);
            *(f16x4*)(sph + (wv * 32 + nt * 16 + lrow) * SP_S + quad * 4) = pv;
        }
        __syncthreads();   // all waves consumed h_step -> epilogue may store

        // ---- epilogue: 256 threads, one (b, col-pair) each ----
        if (tid < 256) {
            float vA = 0.f, vB = 0.f;
#pragma unroll
            for (int s8 = 0; s8 < 8; ++s8) {
                vA += (float)sph[(s8 * 32 + ep_jp * 2    ) * SP_S + ep_bl];
                vB += (float)sph[(s8 * 32 + ep_jp * 2 + 1) * SP_S + ep_bl];
            }
            if (micro == 0) {
                if (ep_sA >= 0) vA += inj[(t * NSENS + ep_sA) * B_DIM + ep_b];
                if (ep_sB >= 0) vB += inj[(t * NSENS + ep_sB) * B_DIM + ep_b];
            }
            union { _Float16 h[2]; unsigned u; } pk;
            pk.h[0] = (_Float16)fmaxf(vA, 0.0f);
            pk.h[1] = (_Float16)fmaxf(vB, 0.0f);
            if (micro == 3) {
                if (ep_uA >= 0) hc[(t * NOUT + ep_uA) * B_DIM + ep_b] = pk.h[0];
                if (ep_uB >= 0) hc[(t * NOUT + ep_uB) * B_DIM + ep_b] = pk.h[1];
            }
            // parity of step+1: even -> sign SET (h>=0, OR sets)
            pk.u |= (step & 1) ? SIGN_M32 : 0u;
            __hip_atomic_store((unsigned*)(bB + ep_off), pk.u,
                               __ATOMIC_RELAXED, __HIP_MEMORY_SCOPE_AGENT);
        }

        // rotate buffers: cur<-next<-third<-cur
        _Float16* tmp = bA; bA = bB; bB = bC; bC = tmp;
    }
}

// ---------------- final readout: out[b][t][o] = hc[t][:][b] . W_out[o][:] + b_out ----

__global__ __launch_bounds__(128)
void k_readout(float* __restrict__ out, const _Float16* __restrict__ hc,
               const float* __restrict__ W_out, const float* __restrict__ b_out) {
    __shared__ _Float16 sh[NOUT * B_DIM];
    const int t = blockIdx.x, tid = threadIdx.x;
    const unsigned int* src = (const unsigned int*)(hc + (size_t)t * NOUT * B_DIM);
    for (int i = tid; i < NOUT * B_DIM / 2; i += 128)
        ((unsigned int*)sh)[i] = src[i];
    __syncthreads();
    const int o = tid >> 6, b = tid & 63;
    float acc = b_out[o];
#pragma unroll 8
    for (int u = 0; u < NOUT; ++u)
        acc += (float)sh[u * B_DIM + b] * W_out[o * NOUT + u];
    out[(b * T_DIM + t) * 2 + o] = acc;
}

// ---------------- host launch ----------------

extern "C" void kernel_launch(void* const* d_in, const int* in_sizes, int n_in,
                              void* d_out, int out_size, void* d_ws, size_t ws_size,
                              hipStream_t stream) {
    const float* inputs = (const float*)d_in[0];
    const float* W_rec  = (const float*)d_in[1];
    const float* W_in   = (const float*)d_in[2];
    const float* b_in   = (const float*)d_in[3];
    const float* W_out  = (const float*)d_in[4];
    const float* b_out  = (const float*)d_in[5];
    const int*   sidx   = (const int*)d_in[6];
    const int*   oidx   = (const int*)d_in[7];

    char* ws = (char*)d_ws;
    float*    inj      = (float*)ws;                           // 8,388,608 B
    _Float16* h0       = (_Float16*)(ws + 8388608);            //   262,144 B
    _Float16* h1       = (_Float16*)(ws + 8388608 + 262144);
    _Float16* h2       = (_Float16*)(ws + 8388608 + 524288);
    _Float16* hc       = (_Float16*)(ws + 8388608 + 786432);   // 2,097,152 B
    int*      inv_sens = (int*)(ws + 8388608 + 786432 + 2097152);
    int*      inv_out  = inv_sens + N_DIM;

    k_init<<<192, 256, 0, stream>>>((uint4*)h0, inv_sens, inv_out);
    k_inv_scatter<<<1, 256, 0, stream>>>(inv_sens, inv_out, sidx, oidx);
    k_inj<<<(T_DIM * NSENS * B_DIM) / 256, 256, 0, stream>>>(inj, inputs, W_in, b_in);

    hipFuncSetAttribute((const void*)rnn_main,
                        hipFuncAttributeMaxDynamicSharedMemorySize, SMEM_MAIN);

    rnn_main<<<NWG, THREADS, SMEM_MAIN, stream>>>(
        W_rec, inj, inv_sens, inv_out, h0, h1, h2, hc);

    k_readout<<<T_DIM, 128, 0, stream>>>((float*)d_out, hc, W_out, b_out);
}